// Round 12
// baseline (4245.193 us; speedup 1.0000x reference)
//
#include <hip/hip_runtime.h>
#include <hip/hip_fp16.h>

#define HD    256
#define TENC  15
#define PLEN  45
#define MROW  64
#define NTHR  1024
#define NBLK  (32768 / MROW)   // 512 blocks, 1 per CU (2 generations)

typedef __attribute__((ext_vector_type(16))) float     f32x16;
typedef __attribute__((ext_vector_type(8)))  _Float16  f16x8;

#define MFMAH __builtin_amdgcn_mfma_f32_32x32x16_f16

__device__ __forceinline__ float fast_sig(float x) {
    float e = __builtin_amdgcn_exp2f(-1.44269504088896f * x);
    return __builtin_amdgcn_rcpf(1.f + e);
}
__device__ __forceinline__ float fast_tanh(float x) {
    float e = __builtin_amdgcn_exp2f(-2.88539008177793f * x);
    return (1.f - e) * __builtin_amdgcn_rcpf(1.f + e);
}

// Transpose W[n_gcols][256] f32 -> fp16 wave-burst layout:
// dst[seg*65536 + ((gc8*16 + kk)*64 + hi*32 + rowA)*8 + e]
__global__ void xpose_w_kernel(const float* __restrict__ src,
                               _Float16* __restrict__ dst, int n_gcols) {
    int t = blockIdx.x * blockDim.x + threadIdx.x;
    if (t >= n_gcols * 32) return;
    int gcol = t >> 5, c8 = t & 31;
    int kk = c8 >> 1, hi = c8 & 1;
    const float* s = src + (size_t)gcol * HD + c8 * 8;
    int seg = gcol >> 8, gc = gcol & 255;
    size_t d = (size_t)seg * 65536 +
               ((size_t)(((gc >> 5) * 16 + kk) * 64 + hi * 32 + (gc & 31))) * 8;
    _Float16 v[8];
    #pragma unroll
    for (int e = 0; e < 8; ++e) v[e] = (_Float16)s[e];
    *(f16x8*)(dst + d) = *(f16x8*)v;
}

// outW [4][256] padded to 32 gate-cols, same layout
__global__ void xpose_ow_kernel(const float* __restrict__ src,
                                _Float16* __restrict__ dst) {
    int t = blockIdx.x * blockDim.x + threadIdx.x;
    if (t >= 32 * 32) return;
    int gcol = t >> 5, c8 = t & 31;
    int kk = c8 >> 1, hi = c8 & 1;
    _Float16 v[8];
    if (gcol < 4) {
        const float* s = src + (size_t)gcol * HD + c8 * 8;
        #pragma unroll
        for (int e = 0; e < 8; ++e) v[e] = (_Float16)s[e];
    } else {
        #pragma unroll
        for (int e = 0; e < 8; ++e) v[e] = (_Float16)0.f;
    }
    size_t d = ((size_t)(kk * 64 + hi * 32 + gcol)) * 8;
    *(f16x8*)(dst + d) = *(f16x8*)v;
}

// Swizzled byte offset into a [64][256] fp16 LDS tile (row stride 512B).
__device__ __forceinline__ int swz(int row, int col) {
    return row * 512 + ((((col >> 3) ^ row) & 31) << 4) + ((col & 7) << 1);
}

__global__ __launch_bounds__(NTHR, 4) void gru_main(
    const float* __restrict__ x,
    const float* __restrict__ eW, const float* __restrict__ eb,
    const _Float16* __restrict__ encWih, const _Float16* __restrict__ encWhh,
    const float* __restrict__ enc_bih, const float* __restrict__ enc_bhh,
    const _Float16* __restrict__ decEW, const float* __restrict__ dec_eb,
    const _Float16* __restrict__ decWih, const _Float16* __restrict__ decWhh,
    const float* __restrict__ dec_bih, const float* __restrict__ dec_bhh,
    const _Float16* __restrict__ outWt, const float* __restrict__ outb,
    float* __restrict__ out)
{
    __shared__ __align__(16) char ls_a[2][MROW * 512];  // 2 x 32KB fp16, swizzled
    __shared__ __align__(16) char ls_h[2][MROW * 512];  // 2 x 32KB fp16, swizzled
    __shared__ float ls_ew[HD * 4];
    __shared__ float ls_eb[HD];
    __shared__ float ls_bias[4 * HD];   // bR, bZ, bN(ih), bH(hh)
    __shared__ float ls_deb[HD];

    const int tid   = threadIdx.x;
    const int lane  = tid & 63;
    const int wv    = tid >> 6;        // 0..15
    const int w7    = wv & 7;          // col-slice
    const int rh    = wv >> 3;         // row-half (0: rows 0-31, 1: rows 32-63)
    const int rowA  = lane & 31;
    const int hi    = lane >> 5;
    const int col   = w7 * 32 + rowA;  // this lane's gate column
    const int nbase = blockIdx.x * MROW;

    for (int i = tid; i < HD * 4; i += NTHR) ls_ew[i] = eW[i];
    if (tid < HD) {
        ls_eb[tid]            = eb[tid];
        ls_bias[tid]          = enc_bih[tid] + enc_bhh[tid];
        ls_bias[HD + tid]     = enc_bih[HD + tid] + enc_bhh[HD + tid];
        ls_bias[2 * HD + tid] = enc_bih[2 * HD + tid];
        ls_bias[3 * HD + tid] = enc_bhh[2 * HD + tid];
    }
    for (int i = tid; i < MROW * 512 / 4; i += NTHR) ((unsigned int*)ls_h[0])[i] = 0u;

    // h carried as packed fp16 pairs: 8 half2 = 8 regs (32 rows x 32 cols / 64 lanes).
    __half2 hpk[8];
    #pragma unroll
    for (int i = 0; i < 8; ++i) hpk[i] = __floats2half2_rn(0.f, 0.f);

    float bR, bZ, bN, bH;   // current-phase biases (enc, then dec)
    float deb, bb;

    // Single-pass accumulators: 4 x f32x16 = 64 VGPRs
    f32x16 accR, accZ, accN1, accN2;

    auto bcast = [](float v) {
        f32x16 a;
        #pragma unroll
        for (int i = 0; i < 16; ++i) a[i] = v;
        return a;
    };

    // gates: single sweep of all 6 weight streams (the FETCH invariant).
    // accR/Z = b + a@W + h@U ; accN1 = bN + a@Wn ; accN2 = bH + h@Un
    auto gates = [&](const _Float16* Wi, const _Float16* Wh, int ar, int hr) {
        accR  = bcast(bR);
        accZ  = bcast(bZ);
        accN1 = bcast(bN);
        accN2 = bcast(bH);
        const char* pA = ls_a[ar] + rowA * 512 + rh * 16384;
        const char* pH = ls_h[hr] + rowA * 512 + rh * 16384;
        const _Float16* bi = Wi + w7 * 8192 + lane * 8;
        const _Float16* bh = Wh + w7 * 8192 + lane * 8;
        #pragma unroll 2
        for (int kk = 0; kk < 16; ++kk) {
            const int sh = (((kk * 2 + hi) ^ rowA) & 31) << 4;
            f16x8 ax = *(const f16x8*)(pA + sh);
            f16x8 ah = *(const f16x8*)(pH + sh);
            const _Float16* ki = bi + kk * 512;
            const _Float16* kh = bh + kk * 512;
            f16x8 bri = *(const f16x8*)(ki);
            f16x8 bzi = *(const f16x8*)(ki + 65536);
            f16x8 bni = *(const f16x8*)(ki + 131072);
            f16x8 brh = *(const f16x8*)(kh);
            f16x8 bzh = *(const f16x8*)(kh + 65536);
            f16x8 bnh = *(const f16x8*)(kh + 131072);
            accR  = MFMAH(ax, bri, accR, 0, 0, 0);
            accZ  = MFMAH(ax, bzi, accZ, 0, 0, 0);
            accN1 = MFMAH(ax, bni, accN1, 0, 0, 0);
            accR  = MFMAH(ah, brh, accR, 0, 0, 0);
            accZ  = MFMAH(ah, bzh, accZ, 0, 0, 0);
            accN2 = MFMAH(ah, bnh, accN2, 0, 0, 0);
        }
    };

    // C/D 32x32 layout: col = lane&31, row(q) = (q&3) + 8*(q>>2) + 4*hi
    auto final_upd = [&]() {
        #pragma unroll
        for (int q = 0; q < 16; q += 2) {
            float2 hv = __half22float2(hpk[q >> 1]);
            float r0 = fast_sig(accR[q]);
            float z0 = fast_sig(accZ[q]);
            float n0 = fast_tanh(fmaf(r0, accN2[q], accN1[q]));
            float h0 = fmaf(z0, hv.x - n0, n0);
            float r1 = fast_sig(accR[q + 1]);
            float z1 = fast_sig(accZ[q + 1]);
            float n1 = fast_tanh(fmaf(r1, accN2[q + 1], accN1[q + 1]));
            float h1 = fmaf(z1, hv.y - n1, n1);
            hpk[q >> 1] = __floats2half2_rn(h0, h1);
        }
    };

    auto write_h = [&](int hw) {
        #pragma unroll
        for (int q = 0; q < 16; q += 2) {
            unsigned int u = *(unsigned int*)&hpk[q >> 1];
            int row = rh * 32 + (q & 3) + ((q >> 2) << 3) + (hi << 2);
            *(unsigned short*)(ls_h[hw] + swz(row, col))     = (unsigned short)u;
            *(unsigned short*)(ls_h[hw] + swz(row + 1, col)) = (unsigned short)(u >> 16);
        }
    };

    auto embed_step = [&](int t, int aw) {
        int row = tid & 63;
        int c0  = (tid >> 6) * 16;
        const float4 xv = *(const float4*)(x + ((size_t)(nbase + row) * TENC + t) * 4);
        #pragma unroll 4
        for (int j = 0; j < 16; ++j) {
            int c = c0 + j;
            const float* wp = &ls_ew[c * 4];
            float v = fmaf(xv.x, wp[0], fmaf(xv.y, wp[1],
                      fmaf(xv.z, wp[2], fmaf(xv.w, wp[3], ls_eb[c]))));
            *(_Float16*)(ls_a[aw] + swz(row, c)) = (_Float16)fmaxf(v, 0.f);
        }
    };

    // dec_in = relu(h[hr] @ dec_embed_W^T + deb) -> ls_a[aw]; all 16 waves
    auto dec_embed = [&](int hr, int aw) {
        f32x16 o = bcast(deb);
        const char* pH = ls_h[hr] + rowA * 512 + rh * 16384;
        const _Float16* be = decEW + w7 * 8192 + lane * 8;
        #pragma unroll 2
        for (int kk = 0; kk < 16; ++kk) {
            const int sh = (((kk * 2 + hi) ^ rowA) & 31) << 4;
            f16x8 a = *(const f16x8*)(pH + sh);
            f16x8 b = *(const f16x8*)(be + kk * 512);
            o = MFMAH(a, b, o, 0, 0, 0);
        }
        #pragma unroll
        for (int q = 0; q < 16; ++q) {
            int row = rh * 32 + (q & 3) + ((q >> 2) << 3) + (hi << 2);
            *(_Float16*)(ls_a[aw] + swz(row, col)) = (_Float16)fmaxf(o[q], 0.f);
        }
    };

    // out = h[hr] @ out_W^T + out_b; waves 0 (rows 0-31) and 8 (rows 32-63)
    auto out_layer = [&](int t, int hr) {
        if (w7 == 0) {
            f32x16 o = bcast(bb);
            const char* pH = ls_h[hr] + rowA * 512 + rh * 16384;
            const _Float16* bo = outWt + lane * 8;
            #pragma unroll 2
            for (int kk = 0; kk < 16; ++kk) {
                const int sh = (((kk * 2 + hi) ^ rowA) & 31) << 4;
                f16x8 a = *(const f16x8*)(pH + sh);
                f16x8 b = *(const f16x8*)(bo + kk * 512);
                o = MFMAH(a, b, o, 0, 0, 0);
            }
            if (rowA < 4) {
                #pragma unroll
                for (int q = 0; q < 16; ++q) {
                    int row = rh * 32 + (q & 3) + ((q >> 2) << 3) + (hi << 2);
                    out[((size_t)(nbase + row) * PLEN + t) * 4 + rowA] = o[q];
                }
            }
        }
    };

    // ---- prologue ----
    __syncthreads();             // staging + ls_h[0] zero visible
    bR = ls_bias[col];
    bZ = ls_bias[HD + col];
    bN = ls_bias[2 * HD + col];
    bH = ls_bias[3 * HD + col];
    embed_step(0, 0);
    __syncthreads();             // ls_a[0] ready

    int ac = 0, hc = 0;

    // ---- encoder: 1 barrier/step (dbuf a and h) ----
    for (int t = 0; t < TENC; ++t) {
        gates(encWih, encWhh, ac, hc);
        final_upd();
        write_h(hc ^ 1);                 // disjoint buffer
        if (t + 1 < TENC) embed_step(t + 1, ac ^ 1);
        __syncthreads();                 // new h + next embed visible
        ac ^= 1; hc ^= 1;
    }

    // ---- encoder -> decoder transition ----
    if (tid < HD) {
        ls_bias[tid]          = dec_bih[tid] + dec_bhh[tid];
        ls_bias[HD + tid]     = dec_bih[HD + tid] + dec_bhh[HD + tid];
        ls_bias[2 * HD + tid] = dec_bih[2 * HD + tid];
        ls_bias[3 * HD + tid] = dec_bhh[2 * HD + tid];
        ls_deb[tid]           = dec_eb[tid];
    }
    __syncthreads();
    bR = ls_bias[col];
    bZ = ls_bias[HD + col];
    bN = ls_bias[2 * HD + col];
    bH = ls_bias[3 * HD + col];
    deb = ls_deb[col];
    bb  = (rowA < 4) ? outb[rowA] : 0.f;
    ac = 0;
    dec_embed(hc, ac);           // dec_in0 from h_enc -> a[0]
    __syncthreads();

    // ---- decoder: 2 barriers/step ----
    for (int t = 0; t < PLEN; ++t) {
        gates(decWih, decWhh, ac, hc);   // reads a[ac], h[hc]
        final_upd();
        write_h(hc ^ 1);                 // h_t into other buffer
        __syncthreads();                 // D1: h_t visible; a[ac] reads done
        dec_embed(hc ^ 1, ac ^ 1);       // dec_in t+1 -> a[ac^1]
        __syncthreads();                 // D2: a[ac^1] ready
        out_layer(t, hc ^ 1);            // overlaps next gates on other waves
        ac ^= 1; hc ^= 1;
    }
}

extern "C" void kernel_launch(void* const* d_in, const int* in_sizes, int n_in,
                              void* d_out, int out_size, void* d_ws, size_t ws_size,
                              hipStream_t stream) {
    const float* x       = (const float*)d_in[0];
    const float* eW      = (const float*)d_in[1];
    const float* eb      = (const float*)d_in[2];
    const float* encWihf = (const float*)d_in[3];
    const float* encWhhf = (const float*)d_in[4];
    const float* enc_bih = (const float*)d_in[5];
    const float* enc_bhh = (const float*)d_in[6];
    const float* decEWf  = (const float*)d_in[7];
    const float* dec_eb  = (const float*)d_in[8];
    const float* decWihf = (const float*)d_in[9];
    const float* decWhhf = (const float*)d_in[10];
    const float* dec_bih = (const float*)d_in[11];
    const float* dec_bhh = (const float*)d_in[12];
    const float* outW    = (const float*)d_in[13];
    const float* outb    = (const float*)d_in[14];

    _Float16* ws = (_Float16*)d_ws;
    _Float16* hWih_e = ws;                  // 3*H*H each
    _Float16* hWhh_e = ws + 196608;
    _Float16* hWih_d = ws + 2 * 196608;
    _Float16* hWhh_d = ws + 3 * 196608;
    _Float16* hEW_d  = ws + 4 * 196608;     // H*H
    _Float16* hOWt   = ws + 4 * 196608 + 65536;  // 32*H

    const int t1 = 768 * 32;
    const int t2 = 256 * 32;
    xpose_w_kernel<<<(t1 + 255) / 256, 256, 0, stream>>>(encWihf, hWih_e, 768);
    xpose_w_kernel<<<(t1 + 255) / 256, 256, 0, stream>>>(encWhhf, hWhh_e, 768);
    xpose_w_kernel<<<(t1 + 255) / 256, 256, 0, stream>>>(decWihf, hWih_d, 768);
    xpose_w_kernel<<<(t1 + 255) / 256, 256, 0, stream>>>(decWhhf, hWhh_d, 768);
    xpose_w_kernel<<<(t2 + 255) / 256, 256, 0, stream>>>(decEWf,  hEW_d,  256);
    xpose_ow_kernel<<<4, 256, 0, stream>>>(outW, hOWt);

    gru_main<<<NBLK, NTHR, 0, stream>>>(
        x, eW, eb, hWih_e, hWhh_e, enc_bih, enc_bhh,
        hEW_d, dec_eb, hWih_d, hWhh_d, dec_bih, dec_bhh,
        hOWt, outb, (float*)d_out);
}

// Round 13
// 2375.690 us; speedup vs baseline: 1.7869x; 1.7869x over previous
//
#include <hip/hip_runtime.h>
#include <hip/hip_fp16.h>

#define HD    256
#define TENC  15
#define PLEN  45
#define MROW  128
#define NTHR  512
#define NBLK  (32768 / MROW)   // 256 blocks = 1 per CU

typedef __attribute__((ext_vector_type(16))) float     f32x16;
typedef __attribute__((ext_vector_type(8)))  _Float16  f16x8;

#define MFMAH __builtin_amdgcn_mfma_f32_32x32x16_f16

__device__ __forceinline__ float fast_sig(float x) {
    float e = __builtin_amdgcn_exp2f(-1.44269504088896f * x);
    return __builtin_amdgcn_rcpf(1.f + e);
}
__device__ __forceinline__ float fast_tanh(float x) {
    float e = __builtin_amdgcn_exp2f(-2.88539008177793f * x);
    return (1.f - e) * __builtin_amdgcn_rcpf(1.f + e);
}

// Transpose W[n_gcols][256] f32 -> fp16 wave-burst layout:
// dst[seg*65536 + ((gc8*16 + kk)*64 + hi*32 + rowA)*8 + e]
__global__ void xpose_w_kernel(const float* __restrict__ src,
                               _Float16* __restrict__ dst, int n_gcols) {
    int t = blockIdx.x * blockDim.x + threadIdx.x;
    if (t >= n_gcols * 32) return;
    int gcol = t >> 5, c8 = t & 31;
    int kk = c8 >> 1, hi = c8 & 1;
    const float* s = src + (size_t)gcol * HD + c8 * 8;
    int seg = gcol >> 8, gc = gcol & 255;
    size_t d = (size_t)seg * 65536 +
               ((size_t)(((gc >> 5) * 16 + kk) * 64 + hi * 32 + (gc & 31))) * 8;
    _Float16 v[8];
    #pragma unroll
    for (int e = 0; e < 8; ++e) v[e] = (_Float16)s[e];
    *(f16x8*)(dst + d) = *(f16x8*)v;
}

// outW [4][256] padded to 32 gate-cols, same layout
__global__ void xpose_ow_kernel(const float* __restrict__ src,
                                _Float16* __restrict__ dst) {
    int t = blockIdx.x * blockDim.x + threadIdx.x;
    if (t >= 32 * 32) return;
    int gcol = t >> 5, c8 = t & 31;
    int kk = c8 >> 1, hi = c8 & 1;
    _Float16 v[8];
    if (gcol < 4) {
        const float* s = src + (size_t)gcol * HD + c8 * 8;
        #pragma unroll
        for (int e = 0; e < 8; ++e) v[e] = (_Float16)s[e];
    } else {
        #pragma unroll
        for (int e = 0; e < 8; ++e) v[e] = (_Float16)0.f;
    }
    size_t d = ((size_t)(kk * 64 + hi * 32 + gcol)) * 8;
    *(f16x8*)(dst + d) = *(f16x8*)v;
}

// Swizzled byte offset into a [128][256] fp16 LDS tile (row stride 512B).
__device__ __forceinline__ int swz(int row, int col) {
    return row * 512 + ((((col >> 3) ^ row) & 31) << 4) + ((col & 7) << 1);
}

__global__ __launch_bounds__(NTHR, 2) void gru_main(
    const float* __restrict__ x,
    const float* __restrict__ eW, const float* __restrict__ eb,
    const _Float16* __restrict__ encWih, const _Float16* __restrict__ encWhh,
    const float* __restrict__ enc_bih, const float* __restrict__ enc_bhh,
    const _Float16* __restrict__ decEW, const float* __restrict__ dec_eb,
    const _Float16* __restrict__ decWih, const _Float16* __restrict__ decWhh,
    const float* __restrict__ dec_bih, const float* __restrict__ dec_bhh,
    const _Float16* __restrict__ outWt, const float* __restrict__ outb,
    float* __restrict__ out)
{
    __shared__ __align__(16) char ls_a[MROW * 512];   // 64KB fp16, swizzled
    __shared__ __align__(16) char ls_h[MROW * 512];   // 64KB fp16, swizzled
    __shared__ float ls_ew[HD * 4];
    __shared__ float ls_eb[HD];
    __shared__ float ls_bias[4 * HD];   // bR, bZ, bN(ih), bH(hh)
    __shared__ float ls_deb[HD];

    const int tid   = threadIdx.x;
    const int lane  = tid & 63;
    const int wv    = tid >> 6;        // 0..7
    const int rowA  = lane & 31;
    const int hi    = lane >> 5;
    const int col   = wv * 32 + rowA;  // this lane's gate column
    const int nbase = blockIdx.x * MROW;

    for (int i = tid; i < HD * 4; i += NTHR) ls_ew[i] = eW[i];
    if (tid < HD) {
        ls_eb[tid]            = eb[tid];
        ls_bias[tid]          = enc_bih[tid] + enc_bhh[tid];
        ls_bias[HD + tid]     = enc_bih[HD + tid] + enc_bhh[HD + tid];
        ls_bias[2 * HD + tid] = enc_bih[2 * HD + tid];
        ls_bias[3 * HD + tid] = enc_bhh[2 * HD + tid];
    }
    for (int i = tid; i < MROW * 512 / 4; i += NTHR) ((unsigned int*)ls_h)[i] = 0u;

    float bR, bZ, bN, bH;   // current-phase biases (enc, then dec)
    float deb, bb;

    // Two-pass accumulators: 8 x f32x16 = 128 (AGPR side of unified file).
    f32x16 accA[4], accB[4];

    const char* pa = ls_a + rowA * 512;
    const char* ph = ls_h + rowA * 512;

    auto bcast = [](float v) {
        f32x16 a;
        #pragma unroll
        for (int i = 0; i < 16; ++i) a[i] = v;
        return a;
    };

    // pass1: accA = bR + a@Wr + h@Ur ; accB = bH + h@Un     (3 B-streams)
    auto pass1 = [&](const _Float16* Wi, const _Float16* Wh) {
        #pragma unroll
        for (int rt = 0; rt < 4; ++rt) { accA[rt] = bcast(bR); accB[rt] = bcast(bH); }
        const _Float16* bi = Wi + wv * 8192 + lane * 8;
        const _Float16* bh = Wh + wv * 8192 + lane * 8;
        #pragma unroll 2
        for (int kk = 0; kk < 16; ++kk) {
            const int sh = (((kk * 2 + hi) ^ rowA) & 31) << 4;
            f16x8 bri = *(const f16x8*)(bi + kk * 512);
            f16x8 brh = *(const f16x8*)(bh + kk * 512);
            f16x8 bnh = *(const f16x8*)(bh + kk * 512 + 131072);
            #pragma unroll
            for (int rt = 0; rt < 4; ++rt) {
                f16x8 ax = *(const f16x8*)(pa + rt * 16384 + sh);
                f16x8 ah = *(const f16x8*)(ph + rt * 16384 + sh);
                accA[rt] = MFMAH(ax, bri, accA[rt], 0, 0, 0);
                accA[rt] = MFMAH(ah, brh, accA[rt], 0, 0, 0);
                accB[rt] = MFMAH(ah, bnh, accB[rt], 0, 0, 0);
            }
        }
    };

    // mid: accB := sig(accA) * accB + bN   (accA freed for pass2)
    auto mid = [&]() {
        #pragma unroll
        for (int rt = 0; rt < 4; ++rt)
            #pragma unroll
            for (int q = 0; q < 16; ++q)
                accB[rt][q] = fmaf(fast_sig(accA[rt][q]), accB[rt][q], bN);
    };

    // pass2: accA = bZ + a@Wz + h@Uz ; accB += a@Wn         (3 B-streams)
    auto pass2 = [&](const _Float16* Wi, const _Float16* Wh) {
        #pragma unroll
        for (int rt = 0; rt < 4; ++rt) accA[rt] = bcast(bZ);
        const _Float16* bi = Wi + wv * 8192 + lane * 8;
        const _Float16* bh = Wh + wv * 8192 + lane * 8;
        #pragma unroll 2
        for (int kk = 0; kk < 16; ++kk) {
            const int sh = (((kk * 2 + hi) ^ rowA) & 31) << 4;
            f16x8 bzi = *(const f16x8*)(bi + kk * 512 + 65536);
            f16x8 bzh = *(const f16x8*)(bh + kk * 512 + 65536);
            f16x8 bni = *(const f16x8*)(bi + kk * 512 + 131072);
            #pragma unroll
            for (int rt = 0; rt < 4; ++rt) {
                f16x8 ax = *(const f16x8*)(pa + rt * 16384 + sh);
                f16x8 ah = *(const f16x8*)(ph + rt * 16384 + sh);
                accA[rt] = MFMAH(ax, bzi, accA[rt], 0, 0, 0);
                accA[rt] = MFMAH(ah, bzh, accA[rt], 0, 0, 0);
                accB[rt] = MFMAH(ax, bni, accB[rt], 0, 0, 0);
            }
        }
    };

    // final: z = sig(accA), n = tanh(accB); h_old read from ls_h (this
    // thread's own elements -> no cross-thread hazard); result -> hpk (transient).
    __half2 hpk[32];
    auto final_upd = [&]() {
        #pragma unroll
        for (int rt = 0; rt < 4; ++rt)
            #pragma unroll
            for (int q = 0; q < 16; q += 2) {
                int row = rt * 32 + (q & 3) + ((q >> 2) << 3) + (hi << 2);
                float h0o = (float)*(const _Float16*)(ls_h + swz(row, col));
                float h1o = (float)*(const _Float16*)(ls_h + swz(row + 1, col));
                float z0 = fast_sig(accA[rt][q]);
                float n0 = fast_tanh(accB[rt][q]);
                float h0 = fmaf(z0, h0o - n0, n0);
                float z1 = fast_sig(accA[rt][q + 1]);
                float n1 = fast_tanh(accB[rt][q + 1]);
                float h1 = fmaf(z1, h1o - n1, n1);
                hpk[rt * 8 + (q >> 1)] = __floats2half2_rn(h0, h1);
            }
    };

    auto write_h = [&]() {
        #pragma unroll
        for (int rt = 0; rt < 4; ++rt)
            #pragma unroll
            for (int q = 0; q < 16; q += 2) {
                unsigned int u = *(unsigned int*)&hpk[rt * 8 + (q >> 1)];
                int row = rt * 32 + (q & 3) + ((q >> 2) << 3) + (hi << 2);
                *(unsigned short*)(ls_h + swz(row, col))     = (unsigned short)u;
                *(unsigned short*)(ls_h + swz(row + 1, col)) = (unsigned short)(u >> 16);
            }
    };

    auto embed_step = [&](int t) {
        int row = tid & 127;
        int c0  = (tid >> 7) * 64;
        const float4 xv = *(const float4*)(x + ((size_t)(nbase + row) * TENC + t) * 4);
        #pragma unroll 8
        for (int j = 0; j < 64; ++j) {
            int c = c0 + j;
            const float* wp = &ls_ew[c * 4];
            float v = fmaf(xv.x, wp[0], fmaf(xv.y, wp[1],
                      fmaf(xv.z, wp[2], fmaf(xv.w, wp[3], ls_eb[c]))));
            *(_Float16*)(ls_a + swz(row, c)) = (_Float16)fmaxf(v, 0.f);
        }
    };

    // dec_in = relu(h @ dec_embed_W^T + deb) -> ls_a; all 8 waves, 4 rowtiles
    auto dec_embed = [&]() {
        f32x16 o0 = bcast(deb), o1 = o0, o2 = o0, o3 = o0;
        const _Float16* be = decEW + wv * 8192 + lane * 8;
        #pragma unroll 2
        for (int kk = 0; kk < 16; ++kk) {
            const int sh = (((kk * 2 + hi) ^ rowA) & 31) << 4;
            f16x8 b = *(const f16x8*)(be + kk * 512);
            o0 = MFMAH(*(const f16x8*)(ph + sh),          b, o0, 0, 0, 0);
            o1 = MFMAH(*(const f16x8*)(ph + 16384 + sh),  b, o1, 0, 0, 0);
            o2 = MFMAH(*(const f16x8*)(ph + 32768 + sh),  b, o2, 0, 0, 0);
            o3 = MFMAH(*(const f16x8*)(ph + 49152 + sh),  b, o3, 0, 0, 0);
        }
        #pragma unroll
        for (int rt = 0; rt < 4; ++rt) {
            const f32x16& o = rt == 0 ? o0 : rt == 1 ? o1 : rt == 2 ? o2 : o3;
            #pragma unroll
            for (int q = 0; q < 16; ++q) {
                int row = rt * 32 + (q & 3) + ((q >> 2) << 3) + (hi << 2);
                *(_Float16*)(ls_a + swz(row, col)) = (_Float16)fmaxf(o[q], 0.f);
            }
        }
    };

    // out = h @ out_W^T + out_b; even waves, rowtile rt = wv>>1
    auto out_layer = [&](int t) {
        if ((wv & 1) == 0) {
            const int rt = wv >> 1;
            f32x16 o = bcast(bb);
            const char* pH = ph + rt * 16384;
            const _Float16* bo = outWt + lane * 8;
            #pragma unroll 2
            for (int kk = 0; kk < 16; ++kk) {
                const int sh = (((kk * 2 + hi) ^ rowA) & 31) << 4;
                f16x8 a = *(const f16x8*)(pH + sh);
                f16x8 b = *(const f16x8*)(bo + kk * 512);
                o = MFMAH(a, b, o, 0, 0, 0);
            }
            if (rowA < 4) {
                #pragma unroll
                for (int q = 0; q < 16; ++q) {
                    int row = rt * 32 + (q & 3) + ((q >> 2) << 3) + (hi << 2);
                    out[((size_t)(nbase + row) * PLEN + t) * 4 + rowA] = o[q];
                }
            }
        }
    };

    // ---- prologue ----
    __syncthreads();             // staging + ls_h zero visible
    bR = ls_bias[col];
    bZ = ls_bias[HD + col];
    bN = ls_bias[2 * HD + col];
    bH = ls_bias[3 * HD + col];
    embed_step(0);
    __syncthreads();             // ls_a ready

    // ---- encoder: 2 barriers/step ----
    for (int t = 0; t < TENC; ++t) {
        pass1(encWih, encWhh);
        mid();
        pass2(encWih, encWhh);
        final_upd();
        __syncthreads();         // all ls_a/ls_h reads done
        write_h();
        if (t + 1 < TENC) embed_step(t + 1);
        __syncthreads();         // new h + next embed visible
    }

    // ---- encoder -> decoder transition ----
    if (tid < HD) {
        ls_bias[tid]          = dec_bih[tid] + dec_bhh[tid];
        ls_bias[HD + tid]     = dec_bih[HD + tid] + dec_bhh[HD + tid];
        ls_bias[2 * HD + tid] = dec_bih[2 * HD + tid];
        ls_bias[3 * HD + tid] = dec_bhh[2 * HD + tid];
        ls_deb[tid]           = dec_eb[tid];
    }
    __syncthreads();
    bR = ls_bias[col];
    bZ = ls_bias[HD + col];
    bN = ls_bias[2 * HD + col];
    bH = ls_bias[3 * HD + col];
    deb = ls_deb[col];
    bb  = (rowA < 4) ? outb[rowA] : 0.f;
    dec_embed();                 // dec_in0 from h_enc
    __syncthreads();

    // ---- decoder: 3 barriers/step ----
    for (int t = 0; t < PLEN; ++t) {
        pass1(decWih, decWhh);
        mid();
        pass2(decWih, decWhh);
        final_upd();
        __syncthreads();         // B1: all reads of ls_a/ls_h done
        write_h();               // h_t
        __syncthreads();         // B2: h_t visible
        dec_embed();             // dec_in t+1 -> ls_a
        __syncthreads();         // B3: ls_a ready
        out_layer(t);            // reads ls_h (stable until next write_h)
    }
}

extern "C" void kernel_launch(void* const* d_in, const int* in_sizes, int n_in,
                              void* d_out, int out_size, void* d_ws, size_t ws_size,
                              hipStream_t stream) {
    const float* x       = (const float*)d_in[0];
    const float* eW      = (const float*)d_in[1];
    const float* eb      = (const float*)d_in[2];
    const float* encWihf = (const float*)d_in[3];
    const float* encWhhf = (const float*)d_in[4];
    const float* enc_bih = (const float*)d_in[5];
    const float* enc_bhh = (const float*)d_in[6];
    const float* decEWf  = (const float*)d_in[7];
    const float* dec_eb  = (const float*)d_in[8];
    const float* decWihf = (const float*)d_in[9];
    const float* decWhhf = (const float*)d_in[10];
    const float* dec_bih = (const float*)d_in[11];
    const float* dec_bhh = (const float*)d_in[12];
    const float* outW    = (const float*)d_in[13];
    const float* outb    = (const float*)d_in[14];

    _Float16* ws = (_Float16*)d_ws;
    _Float16* hWih_e = ws;                  // 3*H*H each
    _Float16* hWhh_e = ws + 196608;
    _Float16* hWih_d = ws + 2 * 196608;
    _Float16* hWhh_d = ws + 3 * 196608;
    _Float16* hEW_d  = ws + 4 * 196608;     // H*H
    _Float16* hOWt   = ws + 4 * 196608 + 65536;  // 32*H

    const int t1 = 768 * 32;
    const int t2 = 256 * 32;
    xpose_w_kernel<<<(t1 + 255) / 256, 256, 0, stream>>>(encWihf, hWih_e, 768);
    xpose_w_kernel<<<(t1 + 255) / 256, 256, 0, stream>>>(encWhhf, hWhh_e, 768);
    xpose_w_kernel<<<(t1 + 255) / 256, 256, 0, stream>>>(decWihf, hWih_d, 768);
    xpose_w_kernel<<<(t1 + 255) / 256, 256, 0, stream>>>(decWhhf, hWhh_d, 768);
    xpose_w_kernel<<<(t2 + 255) / 256, 256, 0, stream>>>(decEWf,  hEW_d,  256);
    xpose_ow_kernel<<<4, 256, 0, stream>>>(outW, hOWt);

    gru_main<<<NBLK, NTHR, 0, stream>>>(
        x, eW, eb, hWih_e, hWhh_e, enc_bih, enc_bhh,
        hEW_d, dec_eb, hWih_d, hWhh_d, dec_bih, dec_bhh,
        hOWt, outb, (float*)d_out);
}